// Round 6
// baseline (458.072 us; speedup 1.0000x reference)
//
#include <hip/hip_runtime.h>

#define B_ 1024
#define N_ 24
#define CI_ 2
#define CO_ 2
#define E_ 256
#define H_ 4
#define DH_ 64

typedef __bf16 v8bf __attribute__((ext_vector_type(8)));
typedef float v4f __attribute__((ext_vector_type(4)));

union Frag {
    uint4 u;
    v8bf v;
};

__device__ __forceinline__ v4f mfma16(v8bf a, v8bf b, v4f c) {
    return __builtin_amdgcn_mfma_f32_16x16x32_bf16(a, b, c, 0, 0, 0);
}

// load 8 consecutive f32 and round to 8 bf16 (for MFMA A fragments)
__device__ __forceinline__ v8bf cvt8(const float* p) {
    float4 a = *(const float4*)p;
    float4 b = *(const float4*)(p + 4);
    v8bf r;
    r[0] = (__bf16)a.x; r[1] = (__bf16)a.y; r[2] = (__bf16)a.z; r[3] = (__bf16)a.w;
    r[4] = (__bf16)b.x; r[5] = (__bf16)b.y; r[6] = (__bf16)b.z; r[7] = (__bf16)b.w;
    return r;
}

// ---------------------------------------------------------------------------
// Kernel T: downcast f32->bf16 + transpose last-two-dims of kernel tensor
// (96 mats of 256x256) and Wq/Wk/Wv (3 mats). [R2-proven, unchanged]
// ws usage total: (3+96)*65536 bf16 = 12.98 MB  (was 38.1 MB -> suspected
// d_ws overflow = the R2..R5 nondeterminism; ctx now lives in d_out).
// ---------------------------------------------------------------------------
__global__ __launch_bounds__(256) void ktrans(
    const float* __restrict__ kern, const float* __restrict__ wq,
    const float* __restrict__ wk, const float* __restrict__ wv,
    __bf16* __restrict__ wt, __bf16* __restrict__ kt) {
    __shared__ __bf16 t[64][65];
    const int blk = blockIdx.x;
    const int mat = blk >> 4, tile = blk & 15;
    const int r0 = (tile >> 2) * 64, c0 = (tile & 3) * 64;
    const float* src;
    __bf16* dst;
    if (mat < 96) {
        src = kern + (size_t)mat * 65536;
        dst = kt + (size_t)mat * 65536;
    } else {
        int p = mat - 96;
        src = (p == 0) ? wq : (p == 1) ? wk : wv;
        dst = wt + (size_t)p * 65536;
    }
    const int tid = threadIdx.x;
#pragma unroll
    for (int k = 0; k < 16; ++k) {
        int idx = k * 256 + tid;
        int e = idx >> 6, f = idx & 63;
        t[f][e] = (__bf16)src[(size_t)(r0 + e) * 256 + c0 + f];
    }
    __syncthreads();
#pragma unroll
    for (int k = 0; k < 16; ++k) {
        int idx = k * 256 + tid;
        int f = idx >> 6, e = idx & 63;
        dst[(size_t)(c0 + f) * 256 + r0 + e] = t[f][e];
    }
}

// ---------------------------------------------------------------------------
// Kernel A: R2-proven structure (512 thr, one b per block, 84 KB LDS).
// Only change vs R2: ctx store is f32 into d_out at layout [b][n][i][f].
// ---------------------------------------------------------------------------
__global__ __launch_bounds__(512) void kattn(
    const float* __restrict__ feat, const __bf16* __restrict__ wt,
    const float* __restrict__ bq, const float* __restrict__ bk,
    const float* __restrict__ bv, float* ctxf) {
    __shared__ __bf16 sQ[CI_][N_][E_];     // 24 KB
    __shared__ __bf16 sK[CI_][N_][E_];     // 24 KB
    __shared__ __bf16 sVT[CI_][E_][N_];    // 24 KB  (V transposed: [f][kn])
    __shared__ __bf16 sP[CI_][H_][N_][32]; // 12 KB  (probs, kn padded to 32)

    const int b = blockIdx.x;
    const int tid = threadIdx.x;
    const int wave = tid >> 6, lane = tid & 63;
    const int quad = lane >> 4, l16 = lane & 15;
    const float* pb[3] = {bq, bk, bv};

    const uint4 zero4 = make_uint4(0u, 0u, 0u, 0u);
    const v4f zf = {0.f, 0.f, 0.f, 0.f};

    // ---------------- Phase 1: QKV projections ----------------
#pragma unroll
    for (int p = 0; p < 3; ++p) {
        const __bf16* W = wt + (size_t)p * 65536;
        v4f acc[4][2];
#pragma unroll
        for (int rf = 0; rf < 4; ++rf)
#pragma unroll
            for (int c = 0; c < 2; ++c) acc[rf][c] = zf;

#pragma unroll
        for (int ks = 0; ks < 8; ++ks) {
            const int kb = ks * 32 + quad * 8;
            Frag a[4], bb[2];
#pragma unroll
            for (int rf = 0; rf < 4; ++rf) {
                const int n = (rf & 1) * 16 + l16;
                const int i = rf >> 1;
                if (n < N_)
                    a[rf].v = cvt8(feat + ((size_t)((b * N_ + n) * CI_ + i)) * E_ + kb);
                else
                    a[rf].u = zero4;
            }
#pragma unroll
            for (int c = 0; c < 2; ++c) {
                const int f0 = (wave * 2 + c) * 16;
                bb[c].u = *(const uint4*)(W + (size_t)(f0 + l16) * E_ + kb);
            }
#pragma unroll
            for (int rf = 0; rf < 4; ++rf)
#pragma unroll
                for (int c = 0; c < 2; ++c)
                    acc[rf][c] = mfma16(a[rf].v, bb[c].v, acc[rf][c]);
        }
        // store to LDS (+bias)
#pragma unroll
        for (int c = 0; c < 2; ++c) {
            const int f = (wave * 2 + c) * 16 + l16;
            const float biasf = pb[p][f];
#pragma unroll
            for (int rf = 0; rf < 4; ++rf) {
#pragma unroll
                for (int r = 0; r < 4; ++r) {
                    const int row = rf * 16 + quad * 4 + r;
                    const int i = row >> 5, np = row & 31;
                    if (np < N_) {
                        const float v = acc[rf][c][r] + biasf;
                        if (p == 0) sQ[i][np][f] = (__bf16)v;
                        else if (p == 1) sK[i][np][f] = (__bf16)v;
                        else sVT[i][f][np] = (__bf16)v;
                    }
                }
            }
        }
    }
    __syncthreads();

    // ---------------- Phase 2: scores + softmax (one (seq,h) per wave) -----
    const int seq = wave >> 2, h = wave & 3;
    v4f sc[2][2];
#pragma unroll
    for (int mt = 0; mt < 2; ++mt)
#pragma unroll
        for (int nt = 0; nt < 2; ++nt) sc[mt][nt] = zf;

#pragma unroll
    for (int ks = 0; ks < 2; ++ks) {
        const int d0 = h * DH_ + ks * 32 + quad * 8;
        Frag a[2], bb[2];
#pragma unroll
        for (int mt = 0; mt < 2; ++mt) {
            const int qn = mt * 16 + l16;
            a[mt].u = (qn < N_) ? *(const uint4*)(&sQ[seq][qn][d0]) : zero4;
        }
#pragma unroll
        for (int nt = 0; nt < 2; ++nt) {
            const int kn = nt * 16 + l16;
            bb[nt].u = (kn < N_) ? *(const uint4*)(&sK[seq][kn][d0]) : zero4;
        }
#pragma unroll
        for (int mt = 0; mt < 2; ++mt)
#pragma unroll
            for (int nt = 0; nt < 2; ++nt)
                sc[mt][nt] = mfma16(a[mt].v, bb[nt].v, sc[mt][nt]);
    }

    const float scale = 0.125f;  // 1/sqrt(64)
#pragma unroll
    for (int mt = 0; mt < 2; ++mt) {
#pragma unroll
        for (int r = 0; r < 4; ++r) {
            const int qn = mt * 16 + quad * 4 + r;
            const float v0 = sc[mt][0][r] * scale;
            const float v1 = (l16 < 8) ? sc[mt][1][r] * scale : -3.0e38f;  // kn>=24 masked
            float mx = fmaxf(v0, v1);
#pragma unroll
            for (int m = 1; m < 16; m <<= 1) mx = fmaxf(mx, __shfl_xor(mx, m));
            const float e0 = __expf(v0 - mx);
            const float e1 = (l16 < 8) ? __expf(v1 - mx) : 0.f;
            float s = e0 + e1;
#pragma unroll
            for (int m = 1; m < 16; m <<= 1) s += __shfl_xor(s, m);
            const float inv = 1.f / s;
            if (qn < N_) {
                sP[seq][h][qn][l16] = (__bf16)(e0 * inv);
                sP[seq][h][qn][16 + l16] = (__bf16)(e1 * inv);
            }
        }
    }
    __syncthreads();  // order sP writes before Phase-3 reads

    // ---------------- Phase 3: ctx = P @ V ----------------
    Frag pa[2], vb[4];
#pragma unroll
    for (int mt = 0; mt < 2; ++mt) {
        const int qn = mt * 16 + l16;
        pa[mt].u = (qn < N_) ? *(const uint4*)(&sP[seq][h][qn][quad * 8]) : zero4;
    }
#pragma unroll
    for (int nt = 0; nt < 4; ++nt) {
        // kn = quad*8+j; quad==3 -> kn in [24,32): P is zero there anyway
        vb[nt].u = (quad < 3) ? *(const uint4*)(&sVT[seq][h * DH_ + nt * 16 + l16][quad * 8]) : zero4;
    }
#pragma unroll
    for (int mt = 0; mt < 2; ++mt) {
#pragma unroll
        for (int nt = 0; nt < 4; ++nt) {
            v4f c0 = zf;
            c0 = mfma16(pa[mt].v, vb[nt].v, c0);
#pragma unroll
            for (int r = 0; r < 4; ++r) {
                const int qn = mt * 16 + quad * 4 + r;
                if (qn < N_) {
                    const int f = h * DH_ + nt * 16 + l16;
                    // f32 ctx into d_out region, layout [b][n][i=seq][f]
                    ctxf[((size_t)((b * N_ + qn) * CI_ + seq)) * E_ + f] = c0[r];
                }
            }
        }
    }
}

// ---------------------------------------------------------------------------
// Kernel P v3: consumes ctx from d_out and overwrites d_out in place.
// Grid (32, 24), 256 thr = 4 waves. Wave (rowgrp = w>>1, half = w&1) owns
// rows [bt*32 + rowgrp*16, +16) x f-cols [half*128, +128) x BOTH o.
// Alias safety: each lane's ctx-read set == its out-write set; all ctx reads
// happen in the GEMM phase; __syncthreads (also needed for the LN partial-sum
// exchange) separates reads from writes. ctxf/out are the same buffer ->
// deliberately NOT __restrict__.
// ---------------------------------------------------------------------------
__global__ __launch_bounds__(256, 3) void kpkln(
    const float* __restrict__ feat, const __bf16* __restrict__ kt,
    const float* ctxf, const float* __restrict__ bias,
    const float* __restrict__ gamma, const float* __restrict__ beta,
    float* out) {
    const int bt = blockIdx.x;  // 0..31
    const int n = blockIdx.y;   // 0..23
    const int tid = threadIdx.x;
    const int wave = tid >> 6, lane = tid & 63;
    const int quad = lane >> 4, l16 = lane & 15;
    const int rowgrp = wave >> 1, half = wave & 1;
    const int rowbase = bt * 32 + rowgrp * 16;

    __shared__ float sS[2][2][32];   // [half][o][row-in-block]
    __shared__ float sS2[2][2][32];

    const v4f zf = {0.f, 0.f, 0.f, 0.f};
    float accf[2][8][4];  // [o][c][r]
#pragma unroll
    for (int o = 0; o < 2; ++o)
#pragma unroll
        for (int c = 0; c < 8; ++c)
#pragma unroll
            for (int r = 0; r < 4; ++r) accf[o][c][r] = 0.f;

#pragma unroll
    for (int i = 0; i < CI_; ++i) {
        const float* A = feat + ((size_t)((rowbase + l16) * N_ + n) * CI_ + i) * E_;
        const __bf16* B0 = kt + ((size_t)((0 * CI_ + i) * N_ + n)) * 65536;
        const __bf16* B1 = kt + ((size_t)((1 * CI_ + i) * N_ + n)) * 65536;
        v4f g0[8], g1[8];
#pragma unroll
        for (int c = 0; c < 8; ++c) { g0[c] = zf; g1[c] = zf; }

#pragma unroll
        for (int ks = 0; ks < 8; ++ks) {
            const int kb = ks * 32 + quad * 8;
            Frag a;
            a.v = cvt8(A + kb);
#pragma unroll
            for (int c = 0; c < 8; ++c) {
                const int fcol = (half * 8 + c) * 16 + l16;
                Frag b0f, b1f;
                b0f.u = *(const uint4*)(B0 + (size_t)fcol * E_ + kb);
                g0[c] = mfma16(a.v, b0f.v, g0[c]);
                b1f.u = *(const uint4*)(B1 + (size_t)fcol * E_ + kb);
                g1[c] = mfma16(a.v, b1f.v, g1[c]);
            }
        }
        // scale by ctx (f32, layout [b][n][i][f]) and accumulate over i
#pragma unroll
        for (int c = 0; c < 8; ++c) {
            const int f = (half * 8 + c) * 16 + l16;
#pragma unroll
            for (int r = 0; r < 4; ++r) {
                const int brow = rowbase + quad * 4 + r;
                const float cv = ctxf[((size_t)((brow * N_ + n) * CI_ + i)) * E_ + f];
                accf[0][c][r] += cv * g0[c][r];
                accf[1][c][r] += cv * g1[c][r];
            }
        }
    }

    // epilogue part 1: +bias +residual, per-(o,row) partial sums over this half
#pragma unroll
    for (int o = 0; o < 2; ++o) {
        const float bno = bias[n * CO_ + o];
#pragma unroll
        for (int r = 0; r < 4; ++r) {
            const int brow = rowbase + quad * 4 + r;
            const float* resid = feat + ((size_t)((brow * N_ + n) * CI_ + o)) * E_;
            float s = 0.f, s2 = 0.f;
#pragma unroll
            for (int c = 0; c < 8; ++c) {
                const int f = (half * 8 + c) * 16 + l16;
                const float v = accf[o][c][r] + bno + resid[f];
                accf[o][c][r] = v;
                s += v;
                s2 += v * v;
            }
#pragma unroll
            for (int m = 1; m < 16; m <<= 1) {
                s += __shfl_xor(s, m);
                s2 += __shfl_xor(s2, m);
            }
            if (l16 == 0) {
                const int row = rowgrp * 16 + quad * 4 + r;
                sS[half][o][row] = s;
                sS2[half][o][row] = s2;
            }
        }
    }
    __syncthreads();  // LN partials visible; also fences ctx reads vs out writes

    // epilogue part 2: combine halves, normalize, write (overwrites ctx slots)
#pragma unroll
    for (int o = 0; o < 2; ++o) {
#pragma unroll
        for (int r = 0; r < 4; ++r) {
            const int row = rowgrp * 16 + quad * 4 + r;
            const int brow = bt * 32 + row;
            const float stot = sS[0][o][row] + sS[1][o][row];
            const float s2tot = sS2[0][o][row] + sS2[1][o][row];
            const float mean = stot * (1.f / 256.f);
            const float var = fmaxf(s2tot * (1.f / 256.f) - mean * mean, 0.f);
            const float rstd = rsqrtf(var + 1e-12f);
            float* op = out + ((size_t)((brow * N_ + n) * CO_ + o)) * E_;
#pragma unroll
            for (int c = 0; c < 8; ++c) {
                const int f = (half * 8 + c) * 16 + l16;
                op[f] = (accf[o][c][r] - mean) * rstd * gamma[f] + beta[f];
            }
        }
    }
}

// ---------------------------------------------------------------------------
extern "C" void kernel_launch(void* const* d_in, const int* in_sizes, int n_in,
                              void* d_out, int out_size, void* d_ws, size_t ws_size,
                              hipStream_t stream) {
    const float* feat = (const float*)d_in[0];
    const float* kern = (const float*)d_in[1];
    const float* bias = (const float*)d_in[2];
    const float* wq = (const float*)d_in[3];
    const float* bq = (const float*)d_in[4];
    const float* wk = (const float*)d_in[5];
    const float* bk = (const float*)d_in[6];
    const float* wv = (const float*)d_in[7];
    const float* bv = (const float*)d_in[8];
    const float* gamma = (const float*)d_in[9];
    const float* beta = (const float*)d_in[10];

    __bf16* ws = (__bf16*)d_ws;
    __bf16* wt = ws;                      // 3 * 65536 bf16
    __bf16* kt = ws + (size_t)3 * 65536;  // 96 * 65536 bf16  (ws total 13 MB)
    float* outctx = (float*)d_out;        // ctx (f32) lives in d_out, then
                                          // kpkln overwrites it in place

    hipLaunchKernelGGL(ktrans, dim3(99 * 16), dim3(256), 0, stream,
                       kern, wq, wk, wv, wt, kt);
    hipLaunchKernelGGL(kattn, dim3(B_), dim3(512), 0, stream,
                       feat, wt, bq, bk, bv, outctx);
    hipLaunchKernelGGL(kpkln, dim3(32, N_), dim3(256), 0, stream,
                       feat, kt, outctx, bias, gamma, beta, outctx);
}

// Round 7
// 440.720 us; speedup vs baseline: 1.0394x; 1.0394x over previous
//
#include <hip/hip_runtime.h>

#define B_ 1024
#define N_ 24
#define CI_ 2
#define CO_ 2
#define E_ 256
#define H_ 4
#define DH_ 64

typedef __bf16 v8bf __attribute__((ext_vector_type(8)));
typedef float v4f __attribute__((ext_vector_type(4)));

union Frag {
    uint4 u;
    v8bf v;
};

__device__ __forceinline__ v4f mfma16(v8bf a, v8bf b, v4f c) {
    return __builtin_amdgcn_mfma_f32_16x16x32_bf16(a, b, c, 0, 0, 0);
}

// load 8 consecutive f32 and round to 8 bf16 (for MFMA A fragments)
__device__ __forceinline__ v8bf cvt8(const float* p) {
    float4 a = *(const float4*)p;
    float4 b = *(const float4*)(p + 4);
    v8bf r;
    r[0] = (__bf16)a.x; r[1] = (__bf16)a.y; r[2] = (__bf16)a.z; r[3] = (__bf16)a.w;
    r[4] = (__bf16)b.x; r[5] = (__bf16)b.y; r[6] = (__bf16)b.z; r[7] = (__bf16)b.w;
    return r;
}

// ---------------------------------------------------------------------------
// Kernel T: downcast f32->bf16 + transpose last-two-dims of kernel tensor
// (96 mats of 256x256) and Wq/Wk/Wv (3 mats). [R2-proven, unchanged]
// ws total: (3+96)*65536 bf16 = 12.98 MB (R6 lesson: stay well under ws_size;
// the old 38 MB layout overflowed d_ws -> nondeterministic corruption).
// ---------------------------------------------------------------------------
__global__ __launch_bounds__(256) void ktrans(
    const float* __restrict__ kern, const float* __restrict__ wq,
    const float* __restrict__ wk, const float* __restrict__ wv,
    __bf16* __restrict__ wt, __bf16* __restrict__ kt) {
    __shared__ __bf16 t[64][65];
    const int blk = blockIdx.x;
    const int mat = blk >> 4, tile = blk & 15;
    const int r0 = (tile >> 2) * 64, c0 = (tile & 3) * 64;
    const float* src;
    __bf16* dst;
    if (mat < 96) {
        src = kern + (size_t)mat * 65536;
        dst = kt + (size_t)mat * 65536;
    } else {
        int p = mat - 96;
        src = (p == 0) ? wq : (p == 1) ? wk : wv;
        dst = wt + (size_t)p * 65536;
    }
    const int tid = threadIdx.x;
#pragma unroll
    for (int k = 0; k < 16; ++k) {
        int idx = k * 256 + tid;
        int e = idx >> 6, f = idx & 63;
        t[f][e] = (__bf16)src[(size_t)(r0 + e) * 256 + c0 + f];
    }
    __syncthreads();
#pragma unroll
    for (int k = 0; k < 16; ++k) {
        int idx = k * 256 + tid;
        int f = idx >> 6, e = idx & 63;
        dst[(size_t)(c0 + f) * 256 + r0 + e] = t[f][e];
    }
}

// ---------------------------------------------------------------------------
// Kernel A v3 (re-applied; R3/R4 failures were the ws overflow, not this
// structure): one (b,seq) per block, 4 waves = 4 heads. Wave h computes QKV
// column slice [64h,64h+64) == its head's d-range. Barriers at phase
// boundaries. LDS 42 KB -> 3 blocks/CU = 12 waves/CU. ctx f32 -> d_out.
// ---------------------------------------------------------------------------
__global__ __launch_bounds__(256, 3) void kattn(
    const float* __restrict__ feat, const __bf16* __restrict__ wt,
    const float* __restrict__ bq, const float* __restrict__ bk,
    const float* __restrict__ bv, float* ctxf) {
    __shared__ __align__(16) __bf16 sQ[N_][E_];      // 12 KB
    __shared__ __align__(16) __bf16 sK[N_][E_];      // 12 KB
    __shared__ __align__(16) __bf16 sVT[E_][N_];     // 12 KB  [f][kn]
    __shared__ __align__(16) __bf16 sP[H_][N_][32];  // 6 KB   [h][qn][kn]

    const int bs = blockIdx.x;  // 0..2047 = b*2+seq
    const int b = bs >> 1, seq = bs & 1;
    const int tid = threadIdx.x;
    const int h = tid >> 6;  // wave == head
    const int lane = tid & 63;
    const int quad = lane >> 4, l16 = lane & 15;
    const float* pb[3] = {bq, bk, bv};

    const uint4 zero4 = make_uint4(0u, 0u, 0u, 0u);
    const v4f zf = {0.f, 0.f, 0.f, 0.f};

    // ---------------- Phase 1: QKV column-slice [64h, 64h+64) -------------
#pragma unroll
    for (int p = 0; p < 3; ++p) {
        const __bf16* W = wt + (size_t)p * 65536;
        v4f acc[2][4];
#pragma unroll
        for (int rf = 0; rf < 2; ++rf)
#pragma unroll
            for (int c = 0; c < 4; ++c) acc[rf][c] = zf;

#pragma unroll
        for (int ks = 0; ks < 8; ++ks) {
            const int kb = ks * 32 + quad * 8;
            Frag a[2], bb[4];
#pragma unroll
            for (int rf = 0; rf < 2; ++rf) {
                const int n = rf * 16 + l16;
                if (n < N_)
                    a[rf].v = cvt8(feat + ((size_t)((b * N_ + n) * CI_ + seq)) * E_ + kb);
                else
                    a[rf].u = zero4;
            }
#pragma unroll
            for (int c = 0; c < 4; ++c) {
                const int f0 = h * DH_ + c * 16;
                bb[c].u = *(const uint4*)(W + (size_t)(f0 + l16) * E_ + kb);
            }
#pragma unroll
            for (int rf = 0; rf < 2; ++rf)
#pragma unroll
                for (int c = 0; c < 4; ++c)
                    acc[rf][c] = mfma16(a[rf].v, bb[c].v, acc[rf][c]);
        }
        // store slice to LDS (+bias); C layout: col=l16, row=quad*4+r
#pragma unroll
        for (int c = 0; c < 4; ++c) {
            const int f = h * DH_ + c * 16 + l16;
            const float biasf = pb[p][f];
#pragma unroll
            for (int rf = 0; rf < 2; ++rf) {
#pragma unroll
                for (int r = 0; r < 4; ++r) {
                    const int n = rf * 16 + quad * 4 + r;
                    if (n < N_) {
                        const float v = acc[rf][c][r] + biasf;
                        if (p == 0) sQ[n][f] = (__bf16)v;
                        else if (p == 1) sK[n][f] = (__bf16)v;
                        else sVT[f][n] = (__bf16)v;
                    }
                }
            }
        }
    }
    __syncthreads();  // fence: QKV stores ordered/visible before phase 2

    // ---------------- Phase 2: scores QK^T/8 + softmax ---------------------
    v4f sc[2][2];
#pragma unroll
    for (int mt = 0; mt < 2; ++mt)
#pragma unroll
        for (int nt = 0; nt < 2; ++nt) sc[mt][nt] = zf;

#pragma unroll
    for (int ks = 0; ks < 2; ++ks) {
        const int d0 = h * DH_ + ks * 32 + quad * 8;
        Frag a[2], bb[2];
#pragma unroll
        for (int mt = 0; mt < 2; ++mt) {
            const int qn = mt * 16 + l16;
            a[mt].u = (qn < N_) ? *(const uint4*)(&sQ[qn][d0]) : zero4;
        }
#pragma unroll
        for (int nt = 0; nt < 2; ++nt) {
            const int kn = nt * 16 + l16;
            bb[nt].u = (kn < N_) ? *(const uint4*)(&sK[kn][d0]) : zero4;
        }
#pragma unroll
        for (int mt = 0; mt < 2; ++mt)
#pragma unroll
            for (int nt = 0; nt < 2; ++nt)
                sc[mt][nt] = mfma16(a[mt].v, bb[nt].v, sc[mt][nt]);
    }

    const float scale = 0.125f;  // 1/sqrt(64)
#pragma unroll
    for (int mt = 0; mt < 2; ++mt) {
#pragma unroll
        for (int r = 0; r < 4; ++r) {
            const int qn = mt * 16 + quad * 4 + r;
            const float v0 = sc[mt][0][r] * scale;
            const float v1 = (l16 < 8) ? sc[mt][1][r] * scale : -3.0e38f;  // kn>=24 masked
            float mx = fmaxf(v0, v1);
#pragma unroll
            for (int m = 1; m < 16; m <<= 1) mx = fmaxf(mx, __shfl_xor(mx, m));
            const float e0 = __expf(v0 - mx);
            const float e1 = (l16 < 8) ? __expf(v1 - mx) : 0.f;
            float s = e0 + e1;
#pragma unroll
            for (int m = 1; m < 16; m <<= 1) s += __shfl_xor(s, m);
            const float inv = 1.f / s;
            if (qn < N_) {
                sP[h][qn][l16] = (__bf16)(e0 * inv);
                sP[h][qn][16 + l16] = (__bf16)(e1 * inv);
            }
        }
    }
    __syncthreads();  // fence: P stores ordered/visible before phase 3

    // ---------------- Phase 3: ctx = P @ V ---------------------------------
    Frag pa[2], vb[4];
#pragma unroll
    for (int mt = 0; mt < 2; ++mt) {
        const int qn = mt * 16 + l16;
        pa[mt].u = (qn < N_) ? *(const uint4*)(&sP[h][qn][quad * 8]) : zero4;
    }
#pragma unroll
    for (int nt = 0; nt < 4; ++nt) {
        // kn = quad*8+j; quad==3 -> kn in [24,32): P is zero there anyway
        vb[nt].u = (quad < 3) ? *(const uint4*)(&sVT[h * DH_ + nt * 16 + l16][quad * 8]) : zero4;
    }
#pragma unroll
    for (int mt = 0; mt < 2; ++mt) {
#pragma unroll
        for (int nt = 0; nt < 4; ++nt) {
            v4f c0 = zf;
            c0 = mfma16(pa[mt].v, vb[nt].v, c0);
#pragma unroll
            for (int r = 0; r < 4; ++r) {
                const int qn = mt * 16 + quad * 4 + r;
                if (qn < N_) {
                    const int f = h * DH_ + nt * 16 + l16;
                    // f32 ctx into d_out region, layout [b][n][i=seq][f]
                    ctxf[((size_t)((b * N_ + qn) * CI_ + seq)) * E_ + f] = c0[r];
                }
            }
        }
    }
}

// ---------------------------------------------------------------------------
// Kernel P v3 [R6-proven, unchanged]: consumes ctx from d_out, overwrites
// d_out in place. Grid (32, 24), 256 thr. Alias safety: each lane's ctx-read
// set == its out-write set; __syncthreads separates reads from writes.
// ---------------------------------------------------------------------------
__global__ __launch_bounds__(256, 3) void kpkln(
    const float* __restrict__ feat, const __bf16* __restrict__ kt,
    const float* ctxf, const float* __restrict__ bias,
    const float* __restrict__ gamma, const float* __restrict__ beta,
    float* out) {
    const int bt = blockIdx.x;  // 0..31
    const int n = blockIdx.y;   // 0..23
    const int tid = threadIdx.x;
    const int wave = tid >> 6, lane = tid & 63;
    const int quad = lane >> 4, l16 = lane & 15;
    const int rowgrp = wave >> 1, half = wave & 1;
    const int rowbase = bt * 32 + rowgrp * 16;

    __shared__ float sS[2][2][32];  // [half][o][row-in-block]
    __shared__ float sS2[2][2][32];

    const v4f zf = {0.f, 0.f, 0.f, 0.f};
    float accf[2][8][4];  // [o][c][r]
#pragma unroll
    for (int o = 0; o < 2; ++o)
#pragma unroll
        for (int c = 0; c < 8; ++c)
#pragma unroll
            for (int r = 0; r < 4; ++r) accf[o][c][r] = 0.f;

#pragma unroll
    for (int i = 0; i < CI_; ++i) {
        const float* A = feat + ((size_t)((rowbase + l16) * N_ + n) * CI_ + i) * E_;
        const __bf16* B0 = kt + ((size_t)((0 * CI_ + i) * N_ + n)) * 65536;
        const __bf16* B1 = kt + ((size_t)((1 * CI_ + i) * N_ + n)) * 65536;
        v4f g0[8], g1[8];
#pragma unroll
        for (int c = 0; c < 8; ++c) { g0[c] = zf; g1[c] = zf; }

#pragma unroll
        for (int ks = 0; ks < 8; ++ks) {
            const int kb = ks * 32 + quad * 8;
            Frag a;
            a.v = cvt8(A + kb);
#pragma unroll
            for (int c = 0; c < 8; ++c) {
                const int fcol = (half * 8 + c) * 16 + l16;
                Frag b0f, b1f;
                b0f.u = *(const uint4*)(B0 + (size_t)fcol * E_ + kb);
                g0[c] = mfma16(a.v, b0f.v, g0[c]);
                b1f.u = *(const uint4*)(B1 + (size_t)fcol * E_ + kb);
                g1[c] = mfma16(a.v, b1f.v, g1[c]);
            }
        }
        // scale by ctx (f32, layout [b][n][i][f]) and accumulate over i
#pragma unroll
        for (int c = 0; c < 8; ++c) {
            const int f = (half * 8 + c) * 16 + l16;
#pragma unroll
            for (int r = 0; r < 4; ++r) {
                const int brow = rowbase + quad * 4 + r;
                const float cv = ctxf[((size_t)((brow * N_ + n) * CI_ + i)) * E_ + f];
                accf[0][c][r] += cv * g0[c][r];
                accf[1][c][r] += cv * g1[c][r];
            }
        }
    }

    // epilogue part 1: +bias +residual, per-(o,row) partial sums over this half
#pragma unroll
    for (int o = 0; o < 2; ++o) {
        const float bno = bias[n * CO_ + o];
#pragma unroll
        for (int r = 0; r < 4; ++r) {
            const int brow = rowbase + quad * 4 + r;
            const float* resid = feat + ((size_t)((brow * N_ + n) * CI_ + o)) * E_;
            float s = 0.f, s2 = 0.f;
#pragma unroll
            for (int c = 0; c < 8; ++c) {
                const int f = (half * 8 + c) * 16 + l16;
                const float v = accf[o][c][r] + bno + resid[f];
                accf[o][c][r] = v;
                s += v;
                s2 += v * v;
            }
#pragma unroll
            for (int m = 1; m < 16; m <<= 1) {
                s += __shfl_xor(s, m);
                s2 += __shfl_xor(s2, m);
            }
            if (l16 == 0) {
                const int row = rowgrp * 16 + quad * 4 + r;
                sS[half][o][row] = s;
                sS2[half][o][row] = s2;
            }
        }
    }
    __syncthreads();  // LN partials visible; also fences ctx reads vs out writes

    // epilogue part 2: combine halves, normalize, write (overwrites ctx slots)
#pragma unroll
    for (int o = 0; o < 2; ++o) {
#pragma unroll
        for (int r = 0; r < 4; ++r) {
            const int row = rowgrp * 16 + quad * 4 + r;
            const int brow = bt * 32 + row;
            const float stot = sS[0][o][row] + sS[1][o][row];
            const float s2tot = sS2[0][o][row] + sS2[1][o][row];
            const float mean = stot * (1.f / 256.f);
            const float var = fmaxf(s2tot * (1.f / 256.f) - mean * mean, 0.f);
            const float rstd = rsqrtf(var + 1e-12f);
            float* op = out + ((size_t)((brow * N_ + n) * CO_ + o)) * E_;
#pragma unroll
            for (int c = 0; c < 8; ++c) {
                const int f = (half * 8 + c) * 16 + l16;
                op[f] = (accf[o][c][r] - mean) * rstd * gamma[f] + beta[f];
            }
        }
    }
}

// ---------------------------------------------------------------------------
extern "C" void kernel_launch(void* const* d_in, const int* in_sizes, int n_in,
                              void* d_out, int out_size, void* d_ws, size_t ws_size,
                              hipStream_t stream) {
    const float* feat = (const float*)d_in[0];
    const float* kern = (const float*)d_in[1];
    const float* bias = (const float*)d_in[2];
    const float* wq = (const float*)d_in[3];
    const float* bq = (const float*)d_in[4];
    const float* wk = (const float*)d_in[5];
    const float* bk = (const float*)d_in[6];
    const float* wv = (const float*)d_in[7];
    const float* bv = (const float*)d_in[8];
    const float* gamma = (const float*)d_in[9];
    const float* beta = (const float*)d_in[10];

    __bf16* ws = (__bf16*)d_ws;
    __bf16* wt = ws;                      // 3 * 65536 bf16
    __bf16* kt = ws + (size_t)3 * 65536;  // 96 * 65536 bf16  (ws total 13 MB)
    float* outctx = (float*)d_out;        // ctx (f32) lives in d_out, then
                                          // kpkln overwrites it in place

    hipLaunchKernelGGL(ktrans, dim3(99 * 16), dim3(256), 0, stream,
                       kern, wq, wk, wv, wt, kt);
    hipLaunchKernelGGL(kattn, dim3(B_ * CI_), dim3(256), 0, stream,
                       feat, wt, bq, bk, bv, outctx);
    hipLaunchKernelGGL(kpkln, dim3(32, N_), dim3(256), 0, stream,
                       feat, kt, outctx, bias, gamma, beta, outctx);
}